// Round 1
// baseline (1441.091 us; speedup 1.0000x reference)
//
#include <hip/hip_runtime.h>
#include <hip/hip_bf16.h>

// MoE forward, MI355X. B=4,S=2048,H=1024,E=8,F=4096,K=2.
// Strategy: router -> gather tokens per expert (128-aligned segments) ->
// grouped bf16 MFMA GEMM1 (gelu) -> grouped GEMM2 -> atomicAdd scatter to out.
// Workspace layout (bytes), total ~312.6 MB:
//   [0,36)        off[9]
//   [128,160)     cnt[8]      (memset 0)
//   [160,192)     cnt2[8]     (memset 0)
//   [256,33024)   e01[8192]
//   [33024,65792) p0[8192]
//   [65792,135424) tok_of_slot[17408] (memset 0xFF -> -1)
//   [135424,..)   Xg bf16 [17408][1024]
//   [35787008,..) W1t bf16 [8][4096][1024]
//   [102895872,..)W2t bf16 [8][1024][4096]
//   [170004736,..)h  bf16 [17408][4096]

typedef __bf16 bf16;
typedef __attribute__((ext_vector_type(4))) __bf16 bf16x4;
typedef __attribute__((ext_vector_type(8))) __bf16 bf16x8;
typedef __attribute__((ext_vector_type(4))) float f32x4;

#define GLD16(g, l) __builtin_amdgcn_global_load_lds( \
    (__attribute__((address_space(1))) void*)(g),      \
    (__attribute__((address_space(3))) void*)(l), 16, 0, 0)

__device__ __forceinline__ float gelu_tanh(float v) {
  float c = 0.7978845608028654f * (v + 0.044715f * v * v * v);
  return 0.5f * v * (1.0f + tanhf(c));
}

// ---------------- router: 1 wave per token ----------------
__global__ __launch_bounds__(256) void router_kernel(
    const float* __restrict__ x, const float* __restrict__ Wr,
    const float* __restrict__ br, int* __restrict__ cnt,
    int* __restrict__ e01, float* __restrict__ p0arr) {
  int wv = threadIdx.x >> 6;
  int l = threadIdx.x & 63;
  int t = blockIdx.x * 4 + wv;
  float acc[8];
#pragma unroll
  for (int e = 0; e < 8; e++) acc[e] = 0.f;
  const float* xr = x + (size_t)t * 1024;
#pragma unroll
  for (int i = 0; i < 16; i++) {
    int h = l + i * 64;
    float xv = xr[h];
    const float4* w4 = (const float4*)(Wr + h * 8);
    float4 wa = w4[0], wb = w4[1];
    acc[0] += xv * wa.x; acc[1] += xv * wa.y; acc[2] += xv * wa.z; acc[3] += xv * wa.w;
    acc[4] += xv * wb.x; acc[5] += xv * wb.y; acc[6] += xv * wb.z; acc[7] += xv * wb.w;
  }
#pragma unroll
  for (int e = 0; e < 8; e++) {
    float v = acc[e];
#pragma unroll
    for (int m = 1; m < 64; m <<= 1) v += __shfl_xor(v, m, 64);
    acc[e] = v + br[e];
  }
  int i1 = 0; float m1 = acc[0];
#pragma unroll
  for (int e = 1; e < 8; e++) { if (acc[e] > m1) { m1 = acc[e]; i1 = e; } }
  int i2 = -1; float m2 = -3.4e38f;
#pragma unroll
  for (int e = 0; e < 8; e++) { if (e != i1 && acc[e] > m2) { m2 = acc[e]; i2 = e; } }
  if (l == 0) {
    e01[t] = i1 | (i2 << 8);
    p0arr[t] = 1.0f / (1.0f + __expf(m2 - m1));  // == p1/(p1+p2) of softmax
    atomicAdd(&cnt[i1], 1);
    atomicAdd(&cnt[i2], 1);
  }
}

// ---------------- 128-aligned segment offsets ----------------
__global__ void offsets_kernel(const int* __restrict__ cnt, int* __restrict__ off) {
  if (threadIdx.x == 0 && blockIdx.x == 0) {
    int a = 0;
    off[0] = 0;
    for (int e = 0; e < 8; e++) { a += (cnt[e] + 127) & ~127; off[e + 1] = a; }
  }
}

// ---------------- scatter: assign slots, gather x -> bf16 ----------------
__global__ __launch_bounds__(256) void scatter_kernel(
    const float* __restrict__ x, const int* __restrict__ e01,
    const int* __restrict__ off, int* __restrict__ cnt2,
    int* __restrict__ tok_of_slot, bf16* __restrict__ Xg) {
  __shared__ int ss[2];
  int t = blockIdx.x;
  if (threadIdx.x == 0) {
    int ee = e01[t];
    int i1 = ee & 255, i2 = (ee >> 8) & 255;
    int s1 = off[i1] + atomicAdd(&cnt2[i1], 1);
    int s2 = off[i2] + atomicAdd(&cnt2[i2], 1);
    tok_of_slot[s1] = t; tok_of_slot[s2] = t;
    ss[0] = s1; ss[1] = s2;
  }
  __syncthreads();
  int s1 = ss[0], s2 = ss[1];
  float4 v = ((const float4*)(x + (size_t)t * 1024))[threadIdx.x];
  bf16x4 bv = { (bf16)v.x, (bf16)v.y, (bf16)v.z, (bf16)v.w };
  *(bf16x4*)(Xg + (size_t)s1 * 1024 + threadIdx.x * 4) = bv;
  *(bf16x4*)(Xg + (size_t)s2 * 1024 + threadIdx.x * 4) = bv;
}

// ---------------- transpose + fp32->bf16: in [E][R][C] -> out [E][C][R] ----
__global__ __launch_bounds__(256) void tconv_kernel(
    const float* __restrict__ in, bf16* __restrict__ out, int R, int C) {
  __shared__ float tile[64][65];
  size_t base = (size_t)blockIdx.z * R * C;
  int gr0 = blockIdx.y * 64, gc0 = blockIdx.x * 64;
#pragma unroll
  for (int i = 0; i < 16; i++) {
    int idx = threadIdx.x + i * 256;
    int r = idx >> 6, c = idx & 63;
    tile[r][c] = in[base + (size_t)(gr0 + r) * C + gc0 + c];
  }
  __syncthreads();
#pragma unroll
  for (int i = 0; i < 16; i++) {
    int idx = threadIdx.x + i * 256;
    int cc = idx >> 6, rr = idx & 63;
    out[base + (size_t)(gc0 + cc) * R + gr0 + rr] = (bf16)tile[rr][cc];
  }
}

// ---------------- grouped GEMM1: h = gelu(Xg @ W1[e] + b1[e]) ----------------
// A: Xg [slots][1024] bf16 (K-contig). B: W1t[e] [4096][1024] bf16 ([N][K]).
__global__ __launch_bounds__(256) void gemm1_kernel(
    const bf16* __restrict__ Xg, const bf16* __restrict__ W1t,
    const float* __restrict__ b1, bf16* __restrict__ hbuf,
    const int* __restrict__ off) {
  __shared__ bf16 As[128 * 64];
  __shared__ bf16 Bs[128 * 64];
  const int K = 1024;
  int row0 = blockIdx.y * 128;
  if (row0 >= off[8]) return;
  int e = 0;
#pragma unroll
  for (int i = 0; i < 8; i++) { if (row0 >= off[i + 1]) e = i + 1; }
  int tid = threadIdx.x;
  int w = tid >> 6, l = tid & 63;
  int mbase = (w >> 1) * 64, nbase = (w & 1) * 64;
  int sr = l >> 3, sc = (l & 7) * 8;
  f32x4 acc[4][4];
#pragma unroll
  for (int a = 0; a < 4; a++)
#pragma unroll
    for (int b = 0; b < 4; b++) acc[a][b] = (f32x4){0.f, 0.f, 0.f, 0.f};
  const bf16* Abase = Xg + (size_t)row0 * K;
  const bf16* Bbase = W1t + ((size_t)e * 4096 + blockIdx.x * 128) * K;
  for (int kt = 0; kt < K / 64; kt++) {
    int k0 = kt * 64;
#pragma unroll
    for (int i = 0; i < 4; i++) {
      int seg = w * 4 + i;
      GLD16(Abase + (size_t)(seg * 8 + sr) * K + k0 + sc, As + seg * 512);
      GLD16(Bbase + (size_t)(seg * 8 + sr) * K + k0 + sc, Bs + seg * 512);
    }
    __syncthreads();
#pragma unroll
    for (int kk = 0; kk < 2; kk++) {
      int ko = kk * 32 + (l >> 4) * 8;
      bf16x8 af[4], bfr[4];
#pragma unroll
      for (int mt = 0; mt < 4; mt++) af[mt] = *(const bf16x8*)&As[(mbase + mt * 16 + (l & 15)) * 64 + ko];
#pragma unroll
      for (int nt = 0; nt < 4; nt++) bfr[nt] = *(const bf16x8*)&Bs[(nbase + nt * 16 + (l & 15)) * 64 + ko];
#pragma unroll
      for (int mt = 0; mt < 4; mt++)
#pragma unroll
        for (int nt = 0; nt < 4; nt++)
          acc[mt][nt] = __builtin_amdgcn_mfma_f32_16x16x32_bf16(af[mt], bfr[nt], acc[mt][nt], 0, 0, 0);
    }
    __syncthreads();
  }
  int col = l & 15, rq = (l >> 4) * 4;
#pragma unroll
  for (int nt = 0; nt < 4; nt++) {
    int gn = blockIdx.x * 128 + nbase + nt * 16 + col;
    float bias = b1[e * 4096 + gn];
#pragma unroll
    for (int mt = 0; mt < 4; mt++) {
#pragma unroll
      for (int j = 0; j < 4; j++) {
        int gm = row0 + mbase + mt * 16 + rq + j;
        float v = acc[mt][nt][j] + bias;
        hbuf[(size_t)gm * 4096 + gn] = (bf16)gelu_tanh(v);
      }
    }
  }
}

// ---------------- grouped GEMM2: out += p0 * (h @ W2[e] + b2[e]) -------------
// A: h [slots][4096] bf16. B: W2t[e] [1024][4096] bf16 ([N][K]).
__global__ __launch_bounds__(256) void gemm2_kernel(
    const bf16* __restrict__ hbuf, const bf16* __restrict__ W2t,
    const float* __restrict__ b2, const int* __restrict__ tok_of_slot,
    const float* __restrict__ p0arr, float* __restrict__ out,
    const int* __restrict__ off) {
  __shared__ bf16 As[128 * 64];
  __shared__ bf16 Bs[128 * 64];
  const int K = 4096;
  int row0 = blockIdx.y * 128;
  if (row0 >= off[8]) return;
  int e = 0;
#pragma unroll
  for (int i = 0; i < 8; i++) { if (row0 >= off[i + 1]) e = i + 1; }
  int tid = threadIdx.x;
  int w = tid >> 6, l = tid & 63;
  int mbase = (w >> 1) * 64, nbase = (w & 1) * 64;
  int sr = l >> 3, sc = (l & 7) * 8;
  f32x4 acc[4][4];
#pragma unroll
  for (int a = 0; a < 4; a++)
#pragma unroll
    for (int b = 0; b < 4; b++) acc[a][b] = (f32x4){0.f, 0.f, 0.f, 0.f};
  const bf16* Abase = hbuf + (size_t)row0 * K;
  const bf16* Bbase = W2t + ((size_t)e * 1024 + blockIdx.x * 128) * K;
  for (int kt = 0; kt < K / 64; kt++) {
    int k0 = kt * 64;
#pragma unroll
    for (int i = 0; i < 4; i++) {
      int seg = w * 4 + i;
      GLD16(Abase + (size_t)(seg * 8 + sr) * K + k0 + sc, As + seg * 512);
      GLD16(Bbase + (size_t)(seg * 8 + sr) * K + k0 + sc, Bs + seg * 512);
    }
    __syncthreads();
#pragma unroll
    for (int kk = 0; kk < 2; kk++) {
      int ko = kk * 32 + (l >> 4) * 8;
      bf16x8 af[4], bfr[4];
#pragma unroll
      for (int mt = 0; mt < 4; mt++) af[mt] = *(const bf16x8*)&As[(mbase + mt * 16 + (l & 15)) * 64 + ko];
#pragma unroll
      for (int nt = 0; nt < 4; nt++) bfr[nt] = *(const bf16x8*)&Bs[(nbase + nt * 16 + (l & 15)) * 64 + ko];
#pragma unroll
      for (int mt = 0; mt < 4; mt++)
#pragma unroll
        for (int nt = 0; nt < 4; nt++)
          acc[mt][nt] = __builtin_amdgcn_mfma_f32_16x16x32_bf16(af[mt], bfr[nt], acc[mt][nt], 0, 0, 0);
    }
    __syncthreads();
  }
  int col = l & 15, rq = (l >> 4) * 4;
#pragma unroll
  for (int mt = 0; mt < 4; mt++) {
#pragma unroll
    for (int j = 0; j < 4; j++) {
      int gm = row0 + mbase + mt * 16 + rq + j;
      int tok = tok_of_slot[gm];
      if (tok < 0) continue;
      float w0 = p0arr[tok];
      float* orow = out + (size_t)tok * 1024;
#pragma unroll
      for (int nt = 0; nt < 4; nt++) {
        int gn = blockIdx.x * 128 + nbase + nt * 16 + col;
        float v = (acc[mt][nt][j] + b2[e * 1024 + gn]) * w0;
        atomicAdd(orow + gn, v);
      }
    }
  }
}

extern "C" void kernel_launch(void* const* d_in, const int* in_sizes, int n_in,
                              void* d_out, int out_size, void* d_ws, size_t ws_size,
                              hipStream_t stream) {
  const float* x  = (const float*)d_in[0];
  const float* Wr = (const float*)d_in[1];
  const float* br = (const float*)d_in[2];
  const float* W1 = (const float*)d_in[3];
  const float* b1 = (const float*)d_in[4];
  const float* W2 = (const float*)d_in[5];
  const float* b2 = (const float*)d_in[6];
  float* out = (float*)d_out;

  char* ws = (char*)d_ws;
  int*   off  = (int*)(ws + 0);
  int*   cnt  = (int*)(ws + 128);
  int*   cnt2 = (int*)(ws + 160);
  int*   e01  = (int*)(ws + 256);
  float* p0   = (float*)(ws + 33024);
  int*   tok  = (int*)(ws + 65792);
  bf16*  Xg   = (bf16*)(ws + 135424);
  bf16*  W1t  = (bf16*)(ws + 35787008ULL);
  bf16*  W2t  = (bf16*)(ws + 102895872ULL);
  bf16*  hb   = (bf16*)(ws + 170004736ULL);
  // requires ws_size >= ~313 MB

  hipMemsetAsync(d_out, 0, (size_t)out_size * 4, stream);
  hipMemsetAsync(ws + 128, 0, 64, stream);
  hipMemsetAsync(tok, 0xFF, 17408 * 4, stream);

  tconv_kernel<<<dim3(64, 16, 8), 256, 0, stream>>>(W1, W1t, 1024, 4096);
  tconv_kernel<<<dim3(16, 64, 8), 256, 0, stream>>>(W2, W2t, 4096, 1024);
  router_kernel<<<2048, 256, 0, stream>>>(x, Wr, br, cnt, e01, p0);
  offsets_kernel<<<1, 64, 0, stream>>>(cnt, off);
  scatter_kernel<<<8192, 256, 0, stream>>>(x, e01, off, cnt2, tok, Xg);
  gemm1_kernel<<<dim3(32, 136), 256, 0, stream>>>(Xg, W1t, b1, hb, off);
  gemm2_kernel<<<dim3(8, 136), 256, 0, stream>>>(hb, W2t, b2, tok, p0, out, off);
}

// Round 3
// 1258.109 us; speedup vs baseline: 1.1454x; 1.1454x over previous
//
#include <hip/hip_runtime.h>
#include <hip/hip_bf16.h>

// MoE forward, MI355X. B=4,S=2048,H=1024,E=8,F=4096,K=2.
// router -> gather per-expert (128-aligned segments) -> grouped bf16 MFMA
// GEMM1 (+gelu) -> grouped GEMM2 (+b2, bf16 y per slot) -> combine (p0*(y1+y2)).
// LDS uses XOR swizzle (colgroup ^= row&7) to kill ds_read_b128 bank conflicts.
// Block->XCD swizzle keeps all N-tiles of an M-row on one XCD L2.
// Workspace (bytes), total ~313 MB:
//   [0,36)            off[9]
//   [128,160)         cnt[8]   (memset 0)
//   [160,192)         cnt2[8]  (memset 0)
//   [256,33024)       e01[8192]
//   [33024,65792)     p0[8192]
//   [65792,98560)     slot1[8192]
//   [98560,131328)    slot2[8192]
//   [131584,35783168) Xg bf16 [17408][1024]  (reused as ybuf bf16 [17408][1024])
//   [35783168,..)     W1t bf16 [8][4096][1024]
//   [102892032,..)    W2t bf16 [8][1024][4096]
//   [170000896,..)    h  bf16 [17408][4096]   (ends 312607232)

typedef __bf16 bf16;
typedef __attribute__((ext_vector_type(4))) __bf16 bf16x4;
typedef __attribute__((ext_vector_type(8))) __bf16 bf16x8;
typedef __attribute__((ext_vector_type(4))) float f32x4;

#define GLD16(g, l) __builtin_amdgcn_global_load_lds( \
    (__attribute__((address_space(1))) void*)(g),      \
    (__attribute__((address_space(3))) void*)(l), 16, 0, 0)

__device__ __forceinline__ float gelu_tanh(float v) {
  float c = 0.7978845608028654f * (v + 0.044715f * v * v * v);
  return 0.5f * v * (1.0f + tanhf(c));
}

// ---------------- router: 1 wave per token ----------------
__global__ __launch_bounds__(256) void router_kernel(
    const float* __restrict__ x, const float* __restrict__ Wr,
    const float* __restrict__ br, int* __restrict__ cnt,
    int* __restrict__ e01, float* __restrict__ p0arr) {
  int wv = threadIdx.x >> 6;
  int l = threadIdx.x & 63;
  int t = blockIdx.x * 4 + wv;
  float acc[8];
#pragma unroll
  for (int e = 0; e < 8; e++) acc[e] = 0.f;
  const float* xr = x + (size_t)t * 1024;
#pragma unroll
  for (int i = 0; i < 16; i++) {
    int h = l + i * 64;
    float xv = xr[h];
    const float4* w4 = (const float4*)(Wr + h * 8);
    float4 wa = w4[0], wb = w4[1];
    acc[0] += xv * wa.x; acc[1] += xv * wa.y; acc[2] += xv * wa.z; acc[3] += xv * wa.w;
    acc[4] += xv * wb.x; acc[5] += xv * wb.y; acc[6] += xv * wb.z; acc[7] += xv * wb.w;
  }
#pragma unroll
  for (int e = 0; e < 8; e++) {
    float v = acc[e];
#pragma unroll
    for (int m = 1; m < 64; m <<= 1) v += __shfl_xor(v, m, 64);
    acc[e] = v + br[e];
  }
  int i1 = 0; float m1 = acc[0];
#pragma unroll
  for (int e = 1; e < 8; e++) { if (acc[e] > m1) { m1 = acc[e]; i1 = e; } }
  int i2 = -1; float m2 = -3.4e38f;
#pragma unroll
  for (int e = 0; e < 8; e++) { if (e != i1 && acc[e] > m2) { m2 = acc[e]; i2 = e; } }
  if (l == 0) {
    e01[t] = i1 | (i2 << 8);
    p0arr[t] = 1.0f / (1.0f + __expf(m2 - m1));  // normalized top-1 prob
    atomicAdd(&cnt[i1], 1);
    atomicAdd(&cnt[i2], 1);
  }
}

// ---------------- 128-aligned segment offsets ----------------
__global__ void offsets_kernel(const int* __restrict__ cnt, int* __restrict__ off) {
  if (threadIdx.x == 0 && blockIdx.x == 0) {
    int a = 0;
    off[0] = 0;
    for (int e = 0; e < 8; e++) { a += (cnt[e] + 127) & ~127; off[e + 1] = a; }
  }
}

// ---------------- scatter: assign slots, gather x -> bf16 ----------------
__global__ __launch_bounds__(256) void scatter_kernel(
    const float* __restrict__ x, const int* __restrict__ e01,
    const int* __restrict__ off, int* __restrict__ cnt2,
    int* __restrict__ slot1, int* __restrict__ slot2, bf16* __restrict__ Xg) {
  __shared__ int ss[2];
  int t = blockIdx.x;
  if (threadIdx.x == 0) {
    int ee = e01[t];
    int i1 = ee & 255, i2 = (ee >> 8) & 255;
    int s1 = off[i1] + atomicAdd(&cnt2[i1], 1);
    int s2 = off[i2] + atomicAdd(&cnt2[i2], 1);
    slot1[t] = s1; slot2[t] = s2;
    ss[0] = s1; ss[1] = s2;
  }
  __syncthreads();
  int s1 = ss[0], s2 = ss[1];
  float4 v = ((const float4*)(x + (size_t)t * 1024))[threadIdx.x];
  bf16x4 bv = { (bf16)v.x, (bf16)v.y, (bf16)v.z, (bf16)v.w };
  *(bf16x4*)(Xg + (size_t)s1 * 1024 + threadIdx.x * 4) = bv;
  *(bf16x4*)(Xg + (size_t)s2 * 1024 + threadIdx.x * 4) = bv;
}

// ---------------- transpose + fp32->bf16: in [E][R][C] -> out [E][C][R] ----
__global__ __launch_bounds__(256) void tconv_kernel(
    const float* __restrict__ in, bf16* __restrict__ out, int R, int C) {
  __shared__ float tile[64][65];
  size_t base = (size_t)blockIdx.z * R * C;
  int gr0 = blockIdx.y * 64, gc0 = blockIdx.x * 64;
#pragma unroll
  for (int i = 0; i < 16; i++) {
    int idx = threadIdx.x + i * 256;
    int r = idx >> 6, c = idx & 63;
    tile[r][c] = in[base + (size_t)(gr0 + r) * C + gc0 + c];
  }
  __syncthreads();
  int rr0 = (threadIdx.x & 15) * 4;
  // 256 threads x 4 iters x bf16x4 = 4096 elements = full 64x64 tile.
#pragma unroll
  for (int i = 0; i < 4; i++) {
    int cc = (threadIdx.x >> 4) + i * 16;
    bf16x4 v = { (bf16)tile[rr0][cc], (bf16)tile[rr0 + 1][cc],
                 (bf16)tile[rr0 + 2][cc], (bf16)tile[rr0 + 3][cc] };
    *(bf16x4*)&out[base + (size_t)(gc0 + cc) * R + gr0 + rr0] = v;
  }
}

// ---------------- grouped GEMM1: h = gelu(Xg @ W1[e] + b1[e]) ----------------
// A: Xg [slots][1024] bf16. B: W1t[e] [4096][1024] bf16 ([N][K]).
// Flat grid 4352: xcd=b&7, j=b>>3; m_tile=xcd*17+j/32, n_tile=j%32.
__global__ __launch_bounds__(256) void gemm1_kernel(
    const bf16* __restrict__ Xg, const bf16* __restrict__ W1t,
    const float* __restrict__ b1, bf16* __restrict__ hbuf,
    const int* __restrict__ off) {
  __shared__ bf16 As[128 * 64];
  __shared__ bf16 Bs[128 * 64];
  const int K = 1024;
  int b = blockIdx.x;
  int xcd = b & 7, j = b >> 3;
  int m_tile = xcd * 17 + (j >> 5);
  int n_tile = j & 31;
  int row0 = m_tile * 128;
  if (row0 >= off[8]) return;
  int e = 0;
#pragma unroll
  for (int i = 0; i < 8; i++) { if (row0 >= off[i + 1]) e = i + 1; }
  int tid = threadIdx.x;
  int w = tid >> 6, l = tid & 63;
  int mbase = (w >> 1) * 64, nbase = (w & 1) * 64;
  int sr = l >> 3;                 // row within 8-row group; row&7 == sr
  int sc = ((l & 7) ^ sr) * 8;     // XOR-swizzled global colgroup
  f32x4 acc[4][4];
#pragma unroll
  for (int a = 0; a < 4; a++)
#pragma unroll
    for (int bb = 0; bb < 4; bb++) acc[a][bb] = (f32x4){0.f, 0.f, 0.f, 0.f};
  const bf16* Abase = Xg + (size_t)row0 * K;
  const bf16* Bbase = W1t + ((size_t)e * 4096 + n_tile * 128) * K;
  for (int kt = 0; kt < K / 64; kt++) {
    int k0 = kt * 64;
#pragma unroll
    for (int i = 0; i < 4; i++) {
      int seg = w * 4 + i;
      GLD16(Abase + (size_t)(seg * 8 + sr) * K + k0 + sc, As + seg * 512);
      GLD16(Bbase + (size_t)(seg * 8 + sr) * K + k0 + sc, Bs + seg * 512);
    }
    __syncthreads();
#pragma unroll
    for (int kk = 0; kk < 2; kk++) {
      bf16x8 af[4], bfr[4];
#pragma unroll
      for (int mt = 0; mt < 4; mt++) {
        int row = mbase + mt * 16 + (l & 15);
        int cg = (kk * 4 + (l >> 4)) ^ (row & 7);
        af[mt] = *(const bf16x8*)&As[row * 64 + cg * 8];
      }
#pragma unroll
      for (int nt = 0; nt < 4; nt++) {
        int row = nbase + nt * 16 + (l & 15);
        int cg = (kk * 4 + (l >> 4)) ^ (row & 7);
        bfr[nt] = *(const bf16x8*)&Bs[row * 64 + cg * 8];
      }
#pragma unroll
      for (int mt = 0; mt < 4; mt++)
#pragma unroll
        for (int nt = 0; nt < 4; nt++)
          acc[mt][nt] = __builtin_amdgcn_mfma_f32_16x16x32_bf16(af[mt], bfr[nt], acc[mt][nt], 0, 0, 0);
    }
    __syncthreads();
  }
  int col = l & 15, rq = (l >> 4) * 4;
#pragma unroll
  for (int nt = 0; nt < 4; nt++) {
    int gn = n_tile * 128 + nbase + nt * 16 + col;
    float bias = b1[e * 4096 + gn];
#pragma unroll
    for (int mt = 0; mt < 4; mt++) {
#pragma unroll
      for (int jj = 0; jj < 4; jj++) {
        int gm = row0 + mbase + mt * 16 + rq + jj;
        float v = acc[mt][nt][jj] + bias;
        hbuf[(size_t)gm * 4096 + gn] = (bf16)gelu_tanh(v);
      }
    }
  }
}

// ---------------- grouped GEMM2: y[slot] = h @ W2[e] + b2[e] (bf16) ---------
// A: h [slots][4096] bf16. B: W2t[e] [1024][4096] bf16 ([N][K]).
// Flat grid 1088: xcd=b&7, j=b>>3; m_tile=xcd*17+j/8, n_tile=j&7.
__global__ __launch_bounds__(256) void gemm2_kernel(
    const bf16* __restrict__ hbuf, const bf16* __restrict__ W2t,
    const float* __restrict__ b2, bf16* __restrict__ yb,
    const int* __restrict__ off) {
  __shared__ bf16 As[128 * 64];
  __shared__ bf16 Bs[128 * 64];
  const int K = 4096;
  int b = blockIdx.x;
  int xcd = b & 7, j = b >> 3;
  int m_tile = xcd * 17 + (j >> 3);
  int n_tile = j & 7;
  int row0 = m_tile * 128;
  if (row0 >= off[8]) return;
  int e = 0;
#pragma unroll
  for (int i = 0; i < 8; i++) { if (row0 >= off[i + 1]) e = i + 1; }
  int tid = threadIdx.x;
  int w = tid >> 6, l = tid & 63;
  int mbase = (w >> 1) * 64, nbase = (w & 1) * 64;
  int sr = l >> 3;
  int sc = ((l & 7) ^ sr) * 8;
  f32x4 acc[4][4];
#pragma unroll
  for (int a = 0; a < 4; a++)
#pragma unroll
    for (int bb = 0; bb < 4; bb++) acc[a][bb] = (f32x4){0.f, 0.f, 0.f, 0.f};
  const bf16* Abase = hbuf + (size_t)row0 * K;
  const bf16* Bbase = W2t + ((size_t)e * 1024 + n_tile * 128) * K;
  for (int kt = 0; kt < K / 64; kt++) {
    int k0 = kt * 64;
#pragma unroll
    for (int i = 0; i < 4; i++) {
      int seg = w * 4 + i;
      GLD16(Abase + (size_t)(seg * 8 + sr) * K + k0 + sc, As + seg * 512);
      GLD16(Bbase + (size_t)(seg * 8 + sr) * K + k0 + sc, Bs + seg * 512);
    }
    __syncthreads();
#pragma unroll
    for (int kk = 0; kk < 2; kk++) {
      bf16x8 af[4], bfr[4];
#pragma unroll
      for (int mt = 0; mt < 4; mt++) {
        int row = mbase + mt * 16 + (l & 15);
        int cg = (kk * 4 + (l >> 4)) ^ (row & 7);
        af[mt] = *(const bf16x8*)&As[row * 64 + cg * 8];
      }
#pragma unroll
      for (int nt = 0; nt < 4; nt++) {
        int row = nbase + nt * 16 + (l & 15);
        int cg = (kk * 4 + (l >> 4)) ^ (row & 7);
        bfr[nt] = *(const bf16x8*)&Bs[row * 64 + cg * 8];
      }
#pragma unroll
      for (int mt = 0; mt < 4; mt++)
#pragma unroll
        for (int nt = 0; nt < 4; nt++)
          acc[mt][nt] = __builtin_amdgcn_mfma_f32_16x16x32_bf16(af[mt], bfr[nt], acc[mt][nt], 0, 0, 0);
    }
    __syncthreads();
  }
  int col = l & 15, rq = (l >> 4) * 4;
#pragma unroll
  for (int nt = 0; nt < 4; nt++) {
    int gn = n_tile * 128 + nbase + nt * 16 + col;
    float bias = b2[e * 1024 + gn];
#pragma unroll
    for (int mt = 0; mt < 4; mt++) {
#pragma unroll
      for (int jj = 0; jj < 4; jj++) {
        int gm = row0 + mbase + mt * 16 + rq + jj;
        yb[(size_t)gm * 1024 + gn] = (bf16)(acc[mt][nt][jj] + bias);
      }
    }
  }
}

// ---------------- combine: out[t] = p0[t] * (y[s1] + y[s2]) -----------------
__global__ __launch_bounds__(256) void combine_kernel(
    const bf16* __restrict__ yb, const int* __restrict__ slot1,
    const int* __restrict__ slot2, const float* __restrict__ p0arr,
    float* __restrict__ out) {
  int t = blockIdx.x;
  int s1 = slot1[t], s2 = slot2[t];
  float w0 = p0arr[t];
  bf16x4 a = *(const bf16x4*)(yb + (size_t)s1 * 1024 + threadIdx.x * 4);
  bf16x4 b = *(const bf16x4*)(yb + (size_t)s2 * 1024 + threadIdx.x * 4);
  float4 o;
  o.x = w0 * ((float)a[0] + (float)b[0]);
  o.y = w0 * ((float)a[1] + (float)b[1]);
  o.z = w0 * ((float)a[2] + (float)b[2]);
  o.w = w0 * ((float)a[3] + (float)b[3]);
  *(float4*)(out + (size_t)t * 1024 + threadIdx.x * 4) = o;
}

extern "C" void kernel_launch(void* const* d_in, const int* in_sizes, int n_in,
                              void* d_out, int out_size, void* d_ws, size_t ws_size,
                              hipStream_t stream) {
  const float* x  = (const float*)d_in[0];
  const float* Wr = (const float*)d_in[1];
  const float* br = (const float*)d_in[2];
  const float* W1 = (const float*)d_in[3];
  const float* b1 = (const float*)d_in[4];
  const float* W2 = (const float*)d_in[5];
  const float* b2 = (const float*)d_in[6];
  float* out = (float*)d_out;

  char* ws = (char*)d_ws;
  int*   off   = (int*)(ws + 0);
  int*   cnt   = (int*)(ws + 128);
  int*   cnt2  = (int*)(ws + 160);
  int*   e01   = (int*)(ws + 256);
  float* p0    = (float*)(ws + 33024);
  int*   slot1 = (int*)(ws + 65792);
  int*   slot2 = (int*)(ws + 98560);
  bf16*  Xg    = (bf16*)(ws + 131584);          // reused as ybuf after gemm1
  bf16*  W1t   = (bf16*)(ws + 35783168ULL);
  bf16*  W2t   = (bf16*)(ws + 102892032ULL);
  bf16*  hb    = (bf16*)(ws + 170000896ULL);
  bf16*  yb    = Xg;

  hipMemsetAsync(ws + 128, 0, 64, stream);

  tconv_kernel<<<dim3(64, 16, 8), 256, 0, stream>>>(W1, W1t, 1024, 4096);
  tconv_kernel<<<dim3(16, 64, 8), 256, 0, stream>>>(W2, W2t, 4096, 1024);
  router_kernel<<<2048, 256, 0, stream>>>(x, Wr, br, cnt, e01, p0);
  offsets_kernel<<<1, 64, 0, stream>>>(cnt, off);
  scatter_kernel<<<8192, 256, 0, stream>>>(x, e01, off, cnt2, slot1, slot2, Xg);
  gemm1_kernel<<<4352, 256, 0, stream>>>(Xg, W1t, b1, hb, off);
  gemm2_kernel<<<1088, 256, 0, stream>>>(hb, W2t, b2, yb, off);
  combine_kernel<<<8192, 256, 0, stream>>>(yb, slot1, slot2, p0, out);
}

// Round 4
// 1156.937 us; speedup vs baseline: 1.2456x; 1.0874x over previous
//
#include <hip/hip_runtime.h>
#include <hip/hip_bf16.h>

// MoE forward, MI355X. B=4,S=2048,H=1024,E=8,F=4096,K=2.
// router -> gather per-expert (128-aligned segments) -> grouped bf16 MFMA
// GEMM1 (+gelu) -> grouped GEMM2 (+b2, bf16 y per slot) -> combine (p0*(y1+y2)).
// GEMM K-loop: BK=32 ping-pong double-buffer in 32 KB LDS (prefetch kt+1 issued
// before compute of kt => compiler's vmcnt(0)@barrier drains mostly-landed loads).
// Global-side XOR swizzle (cg ^= row&3) keeps ds_read_b128 conflict-free.
// Workspace (bytes), total ~313 MB:
//   [0,36) off[9] | [128,160) cnt[8] (memset0) | [160,192) cnt2[8] (memset0)
//   [256,..) e01[8192] | [33024,..) p0[8192] | [65792,..) slot1 | [98560,..) slot2
//   [131584,..)   Xg bf16 [17408][1024] (reused as ybuf)
//   [35783168,..) W1t bf16 [8][4096][1024]
//   [102892032,..)W2t bf16 [8][1024][4096]
//   [170000896,..)h  bf16 [17408][4096]  (ends 312607232)

typedef __bf16 bf16;
typedef __attribute__((ext_vector_type(4))) __bf16 bf16x4;
typedef __attribute__((ext_vector_type(8))) __bf16 bf16x8;
typedef __attribute__((ext_vector_type(4))) float f32x4;

#define GLD16(g, l) __builtin_amdgcn_global_load_lds( \
    (__attribute__((address_space(1))) void*)(g),      \
    (__attribute__((address_space(3))) void*)(l), 16, 0, 0)

__device__ __forceinline__ float gelu_tanh(float v) {
  float c = 0.7978845608028654f * (v + 0.044715f * v * v * v);
  return 0.5f * v * (1.0f + tanhf(c));
}

// ---------------- router: 1 wave per token ----------------
__global__ __launch_bounds__(256) void router_kernel(
    const float* __restrict__ x, const float* __restrict__ Wr,
    const float* __restrict__ br, int* __restrict__ cnt,
    int* __restrict__ e01, float* __restrict__ p0arr) {
  int wv = threadIdx.x >> 6;
  int l = threadIdx.x & 63;
  int t = blockIdx.x * 4 + wv;
  float acc[8];
#pragma unroll
  for (int e = 0; e < 8; e++) acc[e] = 0.f;
  const float* xr = x + (size_t)t * 1024;
#pragma unroll
  for (int i = 0; i < 16; i++) {
    int h = l + i * 64;
    float xv = xr[h];
    const float4* w4 = (const float4*)(Wr + h * 8);
    float4 wa = w4[0], wb = w4[1];
    acc[0] += xv * wa.x; acc[1] += xv * wa.y; acc[2] += xv * wa.z; acc[3] += xv * wa.w;
    acc[4] += xv * wb.x; acc[5] += xv * wb.y; acc[6] += xv * wb.z; acc[7] += xv * wb.w;
  }
#pragma unroll
  for (int e = 0; e < 8; e++) {
    float v = acc[e];
#pragma unroll
    for (int m = 1; m < 64; m <<= 1) v += __shfl_xor(v, m, 64);
    acc[e] = v + br[e];
  }
  int i1 = 0; float m1 = acc[0];
#pragma unroll
  for (int e = 1; e < 8; e++) { if (acc[e] > m1) { m1 = acc[e]; i1 = e; } }
  int i2 = -1; float m2 = -3.4e38f;
#pragma unroll
  for (int e = 0; e < 8; e++) { if (e != i1 && acc[e] > m2) { m2 = acc[e]; i2 = e; } }
  if (l == 0) {
    e01[t] = i1 | (i2 << 8);
    p0arr[t] = 1.0f / (1.0f + __expf(m2 - m1));  // normalized top-1 prob
    atomicAdd(&cnt[i1], 1);
    atomicAdd(&cnt[i2], 1);
  }
}

// ---------------- 128-aligned segment offsets ----------------
__global__ void offsets_kernel(const int* __restrict__ cnt, int* __restrict__ off) {
  if (threadIdx.x == 0 && blockIdx.x == 0) {
    int a = 0;
    off[0] = 0;
    for (int e = 0; e < 8; e++) { a += (cnt[e] + 127) & ~127; off[e + 1] = a; }
  }
}

// ---------------- scatter: assign slots, gather x -> bf16 ----------------
__global__ __launch_bounds__(256) void scatter_kernel(
    const float* __restrict__ x, const int* __restrict__ e01,
    const int* __restrict__ off, int* __restrict__ cnt2,
    int* __restrict__ slot1, int* __restrict__ slot2, bf16* __restrict__ Xg) {
  __shared__ int ss[2];
  int t = blockIdx.x;
  if (threadIdx.x == 0) {
    int ee = e01[t];
    int i1 = ee & 255, i2 = (ee >> 8) & 255;
    int s1 = off[i1] + atomicAdd(&cnt2[i1], 1);
    int s2 = off[i2] + atomicAdd(&cnt2[i2], 1);
    slot1[t] = s1; slot2[t] = s2;
    ss[0] = s1; ss[1] = s2;
  }
  __syncthreads();
  int s1 = ss[0], s2 = ss[1];
  float4 v = ((const float4*)(x + (size_t)t * 1024))[threadIdx.x];
  bf16x4 bv = { (bf16)v.x, (bf16)v.y, (bf16)v.z, (bf16)v.w };
  *(bf16x4*)(Xg + (size_t)s1 * 1024 + threadIdx.x * 4) = bv;
  *(bf16x4*)(Xg + (size_t)s2 * 1024 + threadIdx.x * 4) = bv;
}

// ---------------- transpose + fp32->bf16: in [E][R][C] -> out [E][C][R] ----
__global__ __launch_bounds__(256) void tconv_kernel(
    const float* __restrict__ in, bf16* __restrict__ out, int R, int C) {
  __shared__ float tile[64][65];
  size_t base = (size_t)blockIdx.z * R * C;
  int gr0 = blockIdx.y * 64, gc0 = blockIdx.x * 64;
#pragma unroll
  for (int i = 0; i < 16; i++) {
    int idx = threadIdx.x + i * 256;
    int r = idx >> 6, c = idx & 63;
    tile[r][c] = in[base + (size_t)(gr0 + r) * C + gc0 + c];
  }
  __syncthreads();
  int rr0 = (threadIdx.x & 15) * 4;
  // 256 threads x 4 iters x bf16x4 = full 64x64 tile.
#pragma unroll
  for (int i = 0; i < 4; i++) {
    int cc = (threadIdx.x >> 4) + i * 16;
    bf16x4 v = { (bf16)tile[rr0][cc], (bf16)tile[rr0 + 1][cc],
                 (bf16)tile[rr0 + 2][cc], (bf16)tile[rr0 + 3][cc] };
    *(bf16x4*)&out[base + (size_t)(gc0 + cc) * R + gr0 + rr0] = v;
  }
}

// ======================= GEMM core (BK=32, ping-pong) ========================
// A [M][K], B[N][K], both bf16 K-contig. 128x128 block tile, 4 waves, each
// 64x64 (4x4 of 16x16x32 MFMA). Staging: global-side XOR swizzle cg^=(row&3);
// LDS dest is lane-contiguous (global_load_lds constraint).
// Macro body shared by gemm1/gemm2 via inline function.
struct GemmCtx {
  const bf16* Abase;
  const bf16* Bbase;
  int K;
  int w, l, mbase, nbase;
};

__device__ __forceinline__ void gemm_mainloop(
    const GemmCtx& c, bf16* As0, bf16* As1, bf16* Bs0, bf16* Bs1,
    f32x4 acc[4][4]) {
  const int K = c.K;
  const int NT = K >> 5;
  int w = c.w, l = c.l;
  int gr = w * 32 + (l >> 2);          // this lane's first staged row (of 2)
  int cg = (l & 3) ^ ((l >> 2) & 3);   // global colgroup (XOR swizzle)
  const bf16* Ap = c.Abase + (size_t)gr * K + cg * 8;
  const bf16* Bp = c.Bbase + (size_t)gr * K + cg * 8;
  int ldsoff = w * 1024 + l * 8;       // elements; +512 for second 16-row seg
  // prologue: stage kt=0 into buf0
  {
    GLD16(Ap, As0 + ldsoff);
    GLD16(Ap + (size_t)16 * K, As0 + ldsoff + 512);
    GLD16(Bp, Bs0 + ldsoff);
    GLD16(Bp + (size_t)16 * K, Bs0 + ldsoff + 512);
  }
  int arow[4], brow[4];
#pragma unroll
  for (int t = 0; t < 4; t++) {
    arow[t] = c.mbase + t * 16 + (l & 15);
    brow[t] = c.nbase + t * 16 + (l & 15);
  }
  int kc = l >> 4;  // global colgroup wanted by this lane's fragment
  for (int kt = 0; kt < NT; kt++) {
    __syncthreads();  // vmcnt(0): buf[kt&1] loads (issued last iter) landed
    bf16* Ab = (kt & 1) ? As1 : As0;
    bf16* Bb = (kt & 1) ? Bs1 : Bs0;
    if (kt + 1 < NT) {
      bf16* An = (kt & 1) ? As0 : As1;
      bf16* Bn = (kt & 1) ? Bs0 : Bs1;
      const bf16* Ag = Ap + (size_t)(kt + 1) * 32;
      const bf16* Bg = Bp + (size_t)(kt + 1) * 32;
      GLD16(Ag, An + ldsoff);
      GLD16(Ag + (size_t)16 * K, An + ldsoff + 512);
      GLD16(Bg, Bn + ldsoff);
      GLD16(Bg + (size_t)16 * K, Bn + ldsoff + 512);
    }
    bf16x8 af[4], bfr[4];
#pragma unroll
    for (int t = 0; t < 4; t++) {
      int cgl = kc ^ (arow[t] & 3);
      af[t] = *(const bf16x8*)&Ab[arow[t] * 32 + cgl * 8];
    }
#pragma unroll
    for (int t = 0; t < 4; t++) {
      int cgl = kc ^ (brow[t] & 3);
      bfr[t] = *(const bf16x8*)&Bb[brow[t] * 32 + cgl * 8];
    }
#pragma unroll
    for (int mt = 0; mt < 4; mt++)
#pragma unroll
      for (int nt = 0; nt < 4; nt++)
        acc[mt][nt] = __builtin_amdgcn_mfma_f32_16x16x32_bf16(af[mt], bfr[nt], acc[mt][nt], 0, 0, 0);
  }
}

// ---------------- grouped GEMM1: h = gelu(Xg @ W1[e] + b1[e]) ----------------
// Flat grid 4352: xcd=b&7, j=b>>3; m_tile=xcd*17+j/32, n_tile=j%32.
__global__ __launch_bounds__(256) void gemm1_kernel(
    const bf16* __restrict__ Xg, const bf16* __restrict__ W1t,
    const float* __restrict__ b1, bf16* __restrict__ hbuf,
    const int* __restrict__ off) {
  __shared__ bf16 As0[128 * 32], As1[128 * 32];
  __shared__ bf16 Bs0[128 * 32], Bs1[128 * 32];
  const int K = 1024;
  int b = blockIdx.x;
  int xcd = b & 7, j = b >> 3;
  int m_tile = xcd * 17 + (j >> 5);
  int n_tile = j & 31;
  int row0 = m_tile * 128;
  if (row0 >= off[8]) return;
  int e = 0;
#pragma unroll
  for (int i = 0; i < 8; i++) { if (row0 >= off[i + 1]) e = i + 1; }
  int tid = threadIdx.x;
  GemmCtx c;
  c.w = tid >> 6; c.l = tid & 63;
  c.mbase = (c.w >> 1) * 64; c.nbase = (c.w & 1) * 64;
  c.K = K;
  c.Abase = Xg + (size_t)row0 * K;
  c.Bbase = W1t + ((size_t)e * 4096 + n_tile * 128) * K;
  f32x4 acc[4][4];
#pragma unroll
  for (int a = 0; a < 4; a++)
#pragma unroll
    for (int bb = 0; bb < 4; bb++) acc[a][bb] = (f32x4){0.f, 0.f, 0.f, 0.f};
  gemm_mainloop(c, As0, As1, Bs0, Bs1, acc);
  int l = c.l;
  int col = l & 15, rq = (l >> 4) * 4;
#pragma unroll
  for (int nt = 0; nt < 4; nt++) {
    int gn = n_tile * 128 + c.nbase + nt * 16 + col;
    float bias = b1[e * 4096 + gn];
#pragma unroll
    for (int mt = 0; mt < 4; mt++) {
#pragma unroll
      for (int jj = 0; jj < 4; jj++) {
        int gm = row0 + c.mbase + mt * 16 + rq + jj;
        float v = acc[mt][nt][jj] + bias;
        hbuf[(size_t)gm * 4096 + gn] = (bf16)gelu_tanh(v);
      }
    }
  }
}

// ---------------- grouped GEMM2: y[slot] = h @ W2[e] + b2[e] (bf16) ---------
// Flat grid 1088: xcd=b&7, j=b>>3; m_tile=xcd*17+j/8, n_tile=j&7.
__global__ __launch_bounds__(256) void gemm2_kernel(
    const bf16* __restrict__ hbuf, const bf16* __restrict__ W2t,
    const float* __restrict__ b2, bf16* __restrict__ yb,
    const int* __restrict__ off) {
  __shared__ bf16 As0[128 * 32], As1[128 * 32];
  __shared__ bf16 Bs0[128 * 32], Bs1[128 * 32];
  const int K = 4096;
  int b = blockIdx.x;
  int xcd = b & 7, j = b >> 3;
  int m_tile = xcd * 17 + (j >> 3);
  int n_tile = j & 7;
  int row0 = m_tile * 128;
  if (row0 >= off[8]) return;
  int e = 0;
#pragma unroll
  for (int i = 0; i < 8; i++) { if (row0 >= off[i + 1]) e = i + 1; }
  int tid = threadIdx.x;
  GemmCtx c;
  c.w = tid >> 6; c.l = tid & 63;
  c.mbase = (c.w >> 1) * 64; c.nbase = (c.w & 1) * 64;
  c.K = K;
  c.Abase = hbuf + (size_t)row0 * K;
  c.Bbase = W2t + ((size_t)e * 1024 + n_tile * 128) * K;
  f32x4 acc[4][4];
#pragma unroll
  for (int a = 0; a < 4; a++)
#pragma unroll
    for (int bb = 0; bb < 4; bb++) acc[a][bb] = (f32x4){0.f, 0.f, 0.f, 0.f};
  gemm_mainloop(c, As0, As1, Bs0, Bs1, acc);
  int l = c.l;
  int col = l & 15, rq = (l >> 4) * 4;
#pragma unroll
  for (int nt = 0; nt < 4; nt++) {
    int gn = n_tile * 128 + c.nbase + nt * 16 + col;
    float bias = b2[e * 1024 + gn];
#pragma unroll
    for (int mt = 0; mt < 4; mt++) {
#pragma unroll
      for (int jj = 0; jj < 4; jj++) {
        int gm = row0 + c.mbase + mt * 16 + rq + jj;
        yb[(size_t)gm * 1024 + gn] = (bf16)(acc[mt][nt][jj] + bias);
      }
    }
  }
}

// ---------------- combine: out[t] = p0[t] * (y[s1] + y[s2]) -----------------
__global__ __launch_bounds__(256) void combine_kernel(
    const bf16* __restrict__ yb, const int* __restrict__ slot1,
    const int* __restrict__ slot2, const float* __restrict__ p0arr,
    float* __restrict__ out) {
  int t = blockIdx.x;
  int s1 = slot1[t], s2 = slot2[t];
  float w0 = p0arr[t];
  bf16x4 a = *(const bf16x4*)(yb + (size_t)s1 * 1024 + threadIdx.x * 4);
  bf16x4 b = *(const bf16x4*)(yb + (size_t)s2 * 1024 + threadIdx.x * 4);
  float4 o;
  o.x = w0 * ((float)a[0] + (float)b[0]);
  o.y = w0 * ((float)a[1] + (float)b[1]);
  o.z = w0 * ((float)a[2] + (float)b[2]);
  o.w = w0 * ((float)a[3] + (float)b[3]);
  *(float4*)(out + (size_t)t * 1024 + threadIdx.x * 4) = o;
}

extern "C" void kernel_launch(void* const* d_in, const int* in_sizes, int n_in,
                              void* d_out, int out_size, void* d_ws, size_t ws_size,
                              hipStream_t stream) {
  const float* x  = (const float*)d_in[0];
  const float* Wr = (const float*)d_in[1];
  const float* br = (const float*)d_in[2];
  const float* W1 = (const float*)d_in[3];
  const float* b1 = (const float*)d_in[4];
  const float* W2 = (const float*)d_in[5];
  const float* b2 = (const float*)d_in[6];
  float* out = (float*)d_out;

  char* ws = (char*)d_ws;
  int*   off   = (int*)(ws + 0);
  int*   cnt   = (int*)(ws + 128);
  int*   cnt2  = (int*)(ws + 160);
  int*   e01   = (int*)(ws + 256);
  float* p0    = (float*)(ws + 33024);
  int*   slot1 = (int*)(ws + 65792);
  int*   slot2 = (int*)(ws + 98560);
  bf16*  Xg    = (bf16*)(ws + 131584);          // reused as ybuf after gemm1
  bf16*  W1t   = (bf16*)(ws + 35783168ULL);
  bf16*  W2t   = (bf16*)(ws + 102892032ULL);
  bf16*  hb    = (bf16*)(ws + 170000896ULL);
  bf16*  yb    = Xg;

  hipMemsetAsync(ws + 128, 0, 64, stream);

  tconv_kernel<<<dim3(64, 16, 8), 256, 0, stream>>>(W1, W1t, 1024, 4096);
  tconv_kernel<<<dim3(16, 64, 8), 256, 0, stream>>>(W2, W2t, 4096, 1024);
  router_kernel<<<2048, 256, 0, stream>>>(x, Wr, br, cnt, e01, p0);
  offsets_kernel<<<1, 64, 0, stream>>>(cnt, off);
  scatter_kernel<<<8192, 256, 0, stream>>>(x, e01, off, cnt2, slot1, slot2, Xg);
  gemm1_kernel<<<4352, 256, 0, stream>>>(Xg, W1t, b1, hb, off);
  gemm2_kernel<<<1088, 256, 0, stream>>>(hb, W2t, b2, yb, off);
  combine_kernel<<<8192, 256, 0, stream>>>(yb, slot1, slot2, p0, out);
}